// Round 7
// baseline (1133.290 us; speedup 1.0000x reference)
//
#include <hip/hip_runtime.h>
#include <stdint.h>

#define OUTF 11008
#define INF  4096
#define NG   32      // groups = INF/128
#define TOK  8192
#define KB4  2048    // int32 per qweight row = INF/2

// ---- main GEMM geometry: 256x256 tile, 8 waves, 8-phase, 32x32x16 MFMA ----
#define BM 256
#define BN 256
#define BK 64
#define NT (INF / BK)    // 64 K-tiles
#define GX (OUTF / BN)   // 43
#define GY (TOK / BM)    // 32
#define NWG (GX * GY)    // 1376 = 8 XCD chunks x 172

typedef unsigned short u16;
typedef __attribute__((ext_vector_type(8))) short bf16x8;
typedef __attribute__((ext_vector_type(4))) float f32x4;
typedef __attribute__((ext_vector_type(16))) float f32x16;
typedef __attribute__((ext_vector_type(4))) int i32x4;

// fp32 -> bf16 round-to-nearest-even (inputs finite)
__device__ inline u16 f2bf(float f) {
  union { float f; uint32_t u; } v; v.f = f;
  return (u16)((v.u + 0x7fff + ((v.u >> 16) & 1)) >> 16);
}

// async global->LDS, 16B per lane; lds dest must be wave-uniform base (+lane*16 implicit)
__device__ inline void async_copy16(const void* g, const void* l) {
  __builtin_amdgcn_global_load_lds(
      (__attribute__((address_space(1))) void*)(g),
      (__attribute__((address_space(3))) void*)(l), 16, 0, 0);
}

#define FENCE() asm volatile("" ::: "memory")
#define BAR()   do { FENCE(); __builtin_amdgcn_s_barrier(); FENCE(); } while (0)
#define VMCNT(n) asm volatile("s_waitcnt vmcnt(" #n ")" ::: "memory")

// ---------------- fused preprocessing kernel (unchanged from round 6) ----------------

#define NXU ((long long)TOK * INF / 4)    // 8,388,608
#define NWU ((long long)OUTF * KB4 / 4)   // 5,636,096
#define PREPBLK 2048

__global__ __launch_bounds__(256) void prep(const float* __restrict__ X,
                                            const int* __restrict__ QW,
                                            const float* __restrict__ scales,
                                            const float* __restrict__ zeros,
                                            u16* __restrict__ Xb,
                                            u16* __restrict__ Wb) {
  const long long stride = (long long)gridDim.x * 256;
  for (long long i = (long long)blockIdx.x * 256 + threadIdx.x; i < NXU + NWU;
       i += stride) {
    if (i < NXU) {
      const f32x4 f = __builtin_nontemporal_load((const f32x4*)X + i);
      union { u16 t[4]; uint2 v; } u;
      u.t[0] = f2bf(f[0]); u.t[1] = f2bf(f[1]);
      u.t[2] = f2bf(f[2]); u.t[3] = f2bf(f[3]);
      ((uint2*)Xb)[i] = u.v;
    } else {
      const long long j = i - NXU;          // w-unit: 4 ints of row o
      const int o = (int)(j >> 9);          // 512 units per row (2048/4)
      const int c0 = ((int)j & 511) * 4;    // int column; group = c0/64 (4 | 64)
      const int g = c0 >> 6;
      const float s = scales[o * NG + g];
      const float zs = -zeros[o * NG + g] * s;
      const i32x4 q = __builtin_nontemporal_load((const i32x4*)QW + j);
      union { u16 t[8]; int4 v; } u;
#pragma unroll
      for (int k = 0; k < 4; ++k) {
        u.t[2 * k]     = f2bf(fmaf((float)(q[k] & 15), s, zs));
        u.t[2 * k + 1] = f2bf(fmaf((float)((q[k] >> 4) & 15), s, zs));
      }
      ((int4*)Wb)[j] = u.v;                 // bf16 cols [2*c0, 2*c0+8)
    }
  }
}

// ---------------- main GEMM: r6 schedule, 32x32x16 MFMA ----------------
// Schedule (staging order, counted vmcnt placement, XCD grouping, NT stores)
// is round-6 verbatim -- only the fragment shape changed (16x16x32 -> 32x32x16,
// ceiling 2075 -> 2495 TF, per-tile MFMA floor 2480 -> 2067 cyc/SIMD).
//
// LDS XOR-swizzle: 16B granule g of local row r at g ^ (r&7) (write side via
// pre-swizzled global source + linear gload_lds dest; read side same XOR).
// 32x32x16 fragment mapping:
//   A: m = lane&31, k = (lane>>5)*8 + j   (8 bf16 = one ds_read_b128)
//   B: n = lane&31, k = (lane>>5)*8 + j
//   C/D: col = lane&31, row = (reg&3) + 8*(reg>>2) + 4*(lane>>5), reg in [0,16)
// Per wave per K-tile: 16 A-reads + 8 B-reads (same bytes as 16x16 version),
// 32 MFMA. Phase (KS2, MH) reads A 2mt x 2ks (4) + B 2nt x 2ks (4 on MH0),
// computes 8 MFMA. Bank pattern per 16-lane subgroup identical 2-way-free
// structure to the measured-zero 16x16 layout.
//
// Region/stage/wait schedule (= r6; loads/phase unchanged so audit carries):
//   ph0: B1.h1(t+1)+VMCNT(4)  ph1: A1.mh0(t+1)  ph2: A1.mh1(t+1)
//   ph3: B0.h0(t+2)+VMCNT(4)  ph4: B0.h1(t+2)+VMCNT(4)
//   ph5: A0.mh0(t+2)          ph6: A0.mh1(t+2)  ph7: B1.h0(t+3)+VMCNT(4)
// Waits sit AFTER the MFMA cluster (matrix pipe runs during drain); every
// wait targets loads >=2 phases old; never 0 mid-loop.

__global__ __launch_bounds__(512, 2) void gemm_pre512(const u16* __restrict__ A,
                                                      const u16* __restrict__ B,
                                                      const float* __restrict__ bias,
                                                      float* __restrict__ C) {
  __shared__ __align__(16) u16 As[2][BM * BK];   // 2 x 32 KB
  __shared__ __align__(16) u16 Bs[2][BN * BK];   // 2 x 32 KB  (total 128 KB)
  const int tid = threadIdx.x;
  const int lane = tid & 63;
  const int wid = __builtin_amdgcn_readfirstlane(tid >> 6);

  // XCD-local 2D grouping (r6): XCD k owns bm in [4k,4k+4); 4bm x 8bn walks.
  const int lin = blockIdx.x;
  const int xcd = lin & 7;
  const int wgc = lin >> 3;                 // 0..171
  int bmr, bn;
  if (wgc < 160) {
    const int g = wgc >> 5, r = wgc & 31;
    bn = g * 8 + (r & 7);
    bmr = r >> 3;
  } else {
    const int r = wgc - 160;
    bn = 40 + r % 3;
    bmr = r / 3;
  }
  const int bm = xcd * 4 + bmr;

  const u16* Ab = A + (size_t)bm * BM * INF;
  const u16* Bb = B + (size_t)bn * BN * INF;

  // staging addressing: one global_load_lds (all 8 waves) covers 64 rows
  const int rowoff = tid >> 3;                    // 0..63
  const int gran = (tid & 7) ^ (rowoff & 7);      // pre-swizzled source granule
  const u16* Asrc = Ab + (size_t)rowoff * INF + gran * 8;
  const u16* Bsrc = Bb + (size_t)rowoff * INF + gran * 8;
  const int wid8 = wid * 8;

  // frag addressing (32x32)
  const int rr32 = lane & 31;
  const int hi = lane >> 5;
  const int xr = rr32 & 7;   // row&7 is uniform across mt/MH (tiles are 32-row)
  const int wm = wid >> 2;   // 0..1 -> 128-row half of A tile
  const int wn = wid & 3;    // 0..3 -> 64-row quarter of B tile

  f32x16 acc[4][2] = {};     // [m-tile 0..3][n-tile 0..1], 128 VGPRs
  bf16x8 bq[2][2];           // B frags [nt][ks] for current KS2 (live 2 phases)

// single 64-row staging call (1 VMEM instr/wave; wave w covers rows R0+8w..+7)
#define STAGE1(LDS, SRC, TT, R0)                                               \
  async_copy16((SRC) + (size_t)(R0) * INF + (size_t)(TT) * BK,                 \
               (const char*)(LDS) + ((R0) + wid8) * 128);

// 4 ds_read_b128: A frags [mi][ks] for (KS2, MH) -- rows wm*128+MH*64..+64
#define RD_A(DST, S, KS2, MH)                                                  \
  _Pragma("unroll") for (int mi = 0; mi < 2; ++mi)                             \
    _Pragma("unroll") for (int ks = 0; ks < 2; ++ks)                           \
      DST[mi][ks] = *(const bf16x8*)&As[S][                                    \
          (wm * 128 + ((MH) * 2 + mi) * 32 + rr32) * BK +                      \
          ((((KS2) * 4 + ks * 2 + hi) ^ xr) * 8)];

// 4 ds_read_b128: B frags [ni][ks] for KS2 -- rows wn*64..+64
#define RD_B(DST, S, KS2)                                                      \
  _Pragma("unroll") for (int ni = 0; ni < 2; ++ni)                             \
    _Pragma("unroll") for (int ks = 0; ks < 2; ++ks)                           \
      DST[ni][ks] = *(const bf16x8*)&Bs[S][                                    \
          (wn * 64 + ni * 32 + rr32) * BK +                                    \
          ((((KS2) * 4 + ks * 2 + hi) ^ xr) * 8)];

// 8 x mfma_f32_32x32x16_bf16: quadrant (MH) x both nt x both ks
#define MFMA8(AF, BQ, MH)                                                      \
  do {                                                                         \
    __builtin_amdgcn_s_setprio(1);                                             \
    _Pragma("unroll") for (int ks = 0; ks < 2; ++ks)                           \
      _Pragma("unroll") for (int mi = 0; mi < 2; ++mi)                         \
        _Pragma("unroll") for (int ni = 0; ni < 2; ++ni)                       \
          acc[(MH) * 2 + mi][ni] = __builtin_amdgcn_mfma_f32_32x32x16_bf16(    \
              AF[mi][ks], BQ[ni][ks], acc[(MH) * 2 + mi][ni], 0, 0, 0);        \
    __builtin_amdgcn_s_setprio(0);                                             \
  } while (0)

  // prologue (r6 verbatim): steady-state tail of a virtual previous iter.
  STAGE1(&As[0][0], Asrc, 0, 0)   STAGE1(&As[0][0], Asrc, 0, 128)
  STAGE1(&Bs[0][0], Bsrc, 0, 0)   STAGE1(&Bs[0][0], Bsrc, 0, 64)
  STAGE1(&Bs[0][0], Bsrc, 0, 128) STAGE1(&Bs[0][0], Bsrc, 0, 192)
  STAGE1(&As[0][0], Asrc, 0, 64)  STAGE1(&As[0][0], Asrc, 0, 192)
  STAGE1(&Bs[1][0], Bsrc, 1, 0)   STAGE1(&Bs[1][0], Bsrc, 1, 64)
  VMCNT(4);
  BAR();

  for (int t = 0; t < NT; t += 2) {
    // ph0: slot0 (KS2=0,MH0) | stage B1.h1(t+1) | VMCNT(4) post-MFMA
    {
      bf16x8 af[2][2];
      RD_A(af, 0, 0, 0) RD_B(bq, 0, 0)
      STAGE1(&Bs[1][0], Bsrc, t + 1, 128) STAGE1(&Bs[1][0], Bsrc, t + 1, 192)
      BAR(); MFMA8(af, bq, 0);
      VMCNT(4);
      BAR();
    }
    // ph1: slot0 (KS2=0,MH1) | stage A1.mh0(t+1)
    {
      bf16x8 af[2][2];
      RD_A(af, 0, 0, 1)
      STAGE1(&As[1][0], Asrc, t + 1, 0) STAGE1(&As[1][0], Asrc, t + 1, 128)
      BAR(); MFMA8(af, bq, 1); BAR();
    }
    // ph2: slot0 (KS2=1,MH0) | stage A1.mh1(t+1)
    {
      bf16x8 af[2][2];
      RD_A(af, 0, 1, 0) RD_B(bq, 0, 1)
      STAGE1(&As[1][0], Asrc, t + 1, 64) STAGE1(&As[1][0], Asrc, t + 1, 192)
      BAR(); MFMA8(af, bq, 0); BAR();
    }
    // ph3: slot0 (KS2=1,MH1) | stage B0.h0(t+2) | VMCNT(4) post-MFMA
    {
      bf16x8 af[2][2];
      RD_A(af, 0, 1, 1)
      if (t + 2 < NT) { STAGE1(&Bs[0][0], Bsrc, t + 2, 0) STAGE1(&Bs[0][0], Bsrc, t + 2, 64) }
      BAR(); MFMA8(af, bq, 1);
      if (t + 2 < NT) { VMCNT(4); } else { VMCNT(0); }
      BAR();
    }
    // ph4: slot1 (KS2=0,MH0) | stage B0.h1(t+2) | VMCNT(4) post-MFMA
    {
      bf16x8 af[2][2];
      RD_A(af, 1, 0, 0) RD_B(bq, 1, 0)
      if (t + 2 < NT) { STAGE1(&Bs[0][0], Bsrc, t + 2, 128) STAGE1(&Bs[0][0], Bsrc, t + 2, 192) }
      BAR(); MFMA8(af, bq, 0);
      if (t + 2 < NT) { VMCNT(4); } else { VMCNT(0); }
      BAR();
    }
    // ph5: slot1 (KS2=0,MH1) | stage A0.mh0(t+2)
    {
      bf16x8 af[2][2];
      RD_A(af, 1, 0, 1)
      if (t + 2 < NT) { STAGE1(&As[0][0], Asrc, t + 2, 0) STAGE1(&As[0][0], Asrc, t + 2, 128) }
      BAR(); MFMA8(af, bq, 1); BAR();
    }
    // ph6: slot1 (KS2=1,MH0) | stage A0.mh1(t+2)
    {
      bf16x8 af[2][2];
      RD_A(af, 1, 1, 0) RD_B(bq, 1, 1)
      if (t + 2 < NT) { STAGE1(&As[0][0], Asrc, t + 2, 64) STAGE1(&As[0][0], Asrc, t + 2, 192) }
      BAR(); MFMA8(af, bq, 0); BAR();
    }
    // ph7: slot1 (KS2=1,MH1) | stage B1.h0(t+3) | VMCNT(4) post-MFMA
    {
      bf16x8 af[2][2];
      RD_A(af, 1, 1, 1)
      if (t + 2 < NT) { STAGE1(&Bs[1][0], Bsrc, t + 3, 0) STAGE1(&Bs[1][0], Bsrc, t + 3, 64) }
      BAR(); MFMA8(af, bq, 1);
      if (t + 2 < NT) { VMCNT(4); } else { VMCNT(0); }
      BAR();
    }
  }

  // epilogue: NT stores; 32x32 C/D layout col=lane&31,
  // row = (reg&3) + 8*(reg>>2) + 4*hi
  float bv[2];
#pragma unroll
  for (int ni = 0; ni < 2; ++ni)
    bv[ni] = bias[bn * BN + wn * 64 + ni * 32 + rr32];
#pragma unroll
  for (int mt = 0; mt < 4; ++mt)
#pragma unroll
    for (int ni = 0; ni < 2; ++ni) {
      const int gn = bn * BN + wn * 64 + ni * 32 + rr32;
#pragma unroll
      for (int reg = 0; reg < 16; ++reg) {
        const int gm = bm * BM + wm * 128 + mt * 32 +
                       (reg & 3) + 8 * (reg >> 2) + 4 * hi;
        __builtin_nontemporal_store(acc[mt][ni][reg] + bv[ni],
                                    &C[(size_t)gm * OUTF + gn]);
      }
    }
}

// ---------------- fused fallback (no workspace requirement) ----------------

#define FBM 128
#define FBN 128

#define FMFMA_COMPUTE()                                                       \
  do {                                                                        \
    const int frr = lane & 15;                                                \
    const int fq4 = lane >> 4;                                                \
    _Pragma("unroll") for (int ks = 0; ks < 2; ++ks) {                        \
      bf16x8 fa[4], fb[4];                                                    \
      const int kk = (((ks * 4 + fq4) ^ (frr & 7)) * 8);                      \
      _Pragma("unroll") for (int i = 0; i < 4; ++i) {                         \
        fa[i] = *(const bf16x8*)&Asf[(mwave + i * 16 + frr) * BK + kk];       \
        fb[i] = *(const bf16x8*)&Bsf[(nwave + i * 16 + frr) * BK + kk];       \
      }                                                                       \
      _Pragma("unroll") for (int mi = 0; mi < 4; ++mi)                        \
        _Pragma("unroll") for (int ni = 0; ni < 4; ++ni)                      \
          facc[mi][ni] = __builtin_amdgcn_mfma_f32_16x16x32_bf16(             \
              fa[mi], fb[ni], facc[mi][ni], 0, 0, 0);                         \
    }                                                                         \
  } while (0)

__global__ __launch_bounds__(256) void gemm_fused(const float* __restrict__ X,
                                                  const int* __restrict__ QW,
                                                  const float* __restrict__ scales,
                                                  const float* __restrict__ zeros,
                                                  const float* __restrict__ bias,
                                                  float* __restrict__ C) {
  __shared__ __align__(16) u16 Asf[FBM * BK];
  __shared__ __align__(16) u16 Bsf[FBN * BK];
  const int tid = threadIdx.x;
  const int lane = tid & 63;
  const int wid = tid >> 6;
  const int bm = blockIdx.y, bn = blockIdx.x;
  const int row = tid >> 1;
  const int half = tid & 1;
  const float* xr = X + (size_t)(bm * FBM + row) * INF + half * 32;
  const int* qr = QW + (size_t)(bn * FBN + row) * KB4 + half * 16;
  const float* srow = scales + (size_t)(bn * FBN + row) * NG;
  const float* zrow = zeros + (size_t)(bn * FBN + row) * NG;
  const int mwave = (wid >> 1) * 64;
  const int nwave = (wid & 1) * 64;
  f32x4 facc[4][4] = {};

  for (int kb = 0; kb < INF / BK; ++kb) {
    const int k0 = kb * BK;
    union { u16 t[32]; int4 v[4]; } ta, tb;
#pragma unroll
    for (int j = 0; j < 8; ++j) {
      const float4 f = *(const float4*)(xr + k0 + j * 4);
      ta.t[4 * j]     = f2bf(f.x);
      ta.t[4 * j + 1] = f2bf(f.y);
      ta.t[4 * j + 2] = f2bf(f.z);
      ta.t[4 * j + 3] = f2bf(f.w);
    }
    {
      const float s = srow[kb >> 1];
      const float zs = -zrow[kb >> 1] * s;
#pragma unroll
      for (int j = 0; j < 4; ++j) {
        const int4 q = *(const int4*)(qr + kb * 32 + j * 4);
        const int qq[4] = {q.x, q.y, q.z, q.w};
#pragma unroll
        for (int u = 0; u < 4; ++u) {
          tb.t[8 * j + 2 * u]     = f2bf(fmaf((float)(qq[u] & 15), s, zs));
          tb.t[8 * j + 2 * u + 1] = f2bf(fmaf((float)((qq[u] >> 4) & 15), s, zs));
        }
      }
    }
    __syncthreads();
#pragma unroll
    for (int j = 0; j < 4; ++j) {
      *(int4*)&Asf[row * BK + (((half * 4 + j) ^ (row & 7)) * 8)] = ta.v[j];
      *(int4*)&Bsf[row * BK + (((half * 4 + j) ^ (row & 7)) * 8)] = tb.v[j];
    }
    __syncthreads();
    FMFMA_COMPUTE();
  }
  {
    const int ncol = lane & 15;
    const int qrow = (lane >> 4) * 4;
#pragma unroll
    for (int mi = 0; mi < 4; ++mi)
#pragma unroll
      for (int ni = 0; ni < 4; ++ni) {
        const int gn = bn * FBN + nwave + ni * 16 + ncol;
        const float bvv = bias[gn];
#pragma unroll
        for (int r = 0; r < 4; ++r) {
          const int gm = bm * FBM + mwave + mi * 16 + qrow + r;
          C[(size_t)gm * OUTF + gn] = facc[mi][ni][r] + bvv;
        }
      }
  }
}

// ---------------- launch ----------------

extern "C" void kernel_launch(void* const* d_in, const int* in_sizes, int n_in,
                              void* d_out, int out_size, void* d_ws, size_t ws_size,
                              hipStream_t stream) {
  const float* x = (const float*)d_in[0];
  const int* qw = (const int*)d_in[1];
  const float* scales = (const float*)d_in[2];
  const float* zeros = (const float*)d_in[3];
  const float* bias = (const float*)d_in[4];
  float* out = (float*)d_out;

  const size_t needW = (size_t)OUTF * INF * sizeof(u16);  // 90,177,536 B
  const size_t needX = (size_t)TOK * INF * sizeof(u16);   // 67,108,864 B

  if (ws_size >= needW + needX) {
    u16* Wb = (u16*)d_ws;
    u16* Xb = (u16*)((char*)d_ws + needW);
    prep<<<PREPBLK, 256, 0, stream>>>(x, qw, scales, zeros, Xb, Wb);
    gemm_pre512<<<dim3(NWG), 512, 0, stream>>>(Xb, Wb, bias, out);
  } else {
    gemm_fused<<<dim3(OUTF / FBN, TOK / FBM), 256, 0, stream>>>(x, qw, scales, zeros, bias, out);
  }
}

// Round 8
// 1105.737 us; speedup vs baseline: 1.0249x; 1.0249x over previous
//
#include <hip/hip_runtime.h>
#include <stdint.h>

#define OUTF 11008
#define INF  4096
#define NG   32      // groups = INF/128
#define TOK  8192
#define KB4  2048    // int32 per qweight row = INF/2

// ---- main GEMM geometry: 256x256 tile, 8 waves, 8-phase, 32x32x16 MFMA ----
#define BM 256
#define BN 256
#define BK 64
#define NT (INF / BK)    // 64 K-tiles
#define GX (OUTF / BN)   // 43
#define GY (TOK / BM)    // 32
#define NWG (GX * GY)    // 1376 = 8 XCD chunks x 172

typedef unsigned short u16;
typedef __attribute__((ext_vector_type(8))) short bf16x8;
typedef __attribute__((ext_vector_type(4))) float f32x4;
typedef __attribute__((ext_vector_type(16))) float f32x16;
typedef __attribute__((ext_vector_type(4))) int i32x4;

// fp32 -> bf16 round-to-nearest-even (inputs finite)
__device__ inline u16 f2bf(float f) {
  union { float f; uint32_t u; } v; v.f = f;
  return (u16)((v.u + 0x7fff + ((v.u >> 16) & 1)) >> 16);
}

// async global->LDS, 16B per lane; lds dest must be wave-uniform base (+lane*16 implicit)
__device__ inline void async_copy16(const void* g, const void* l) {
  __builtin_amdgcn_global_load_lds(
      (__attribute__((address_space(1))) void*)(g),
      (__attribute__((address_space(3))) void*)(l), 16, 0, 0);
}

#define FENCE() asm volatile("" ::: "memory")
#define BAR()   do { FENCE(); __builtin_amdgcn_s_barrier(); FENCE(); } while (0)
#define VMCNT(n) asm volatile("s_waitcnt vmcnt(" #n ")" ::: "memory")

// ---------------- fused preprocessing kernel (unchanged from round 6) ----------------

#define NXU ((long long)TOK * INF / 4)    // 8,388,608
#define NWU ((long long)OUTF * KB4 / 4)   // 5,636,096
#define PREPBLK 2048

__global__ __launch_bounds__(256) void prep(const float* __restrict__ X,
                                            const int* __restrict__ QW,
                                            const float* __restrict__ scales,
                                            const float* __restrict__ zeros,
                                            u16* __restrict__ Xb,
                                            u16* __restrict__ Wb) {
  const long long stride = (long long)gridDim.x * 256;
  for (long long i = (long long)blockIdx.x * 256 + threadIdx.x; i < NXU + NWU;
       i += stride) {
    if (i < NXU) {
      const f32x4 f = __builtin_nontemporal_load((const f32x4*)X + i);
      union { u16 t[4]; uint2 v; } u;
      u.t[0] = f2bf(f[0]); u.t[1] = f2bf(f[1]);
      u.t[2] = f2bf(f[2]); u.t[3] = f2bf(f[3]);
      ((uint2*)Xb)[i] = u.v;
    } else {
      const long long j = i - NXU;          // w-unit: 4 ints of row o
      const int o = (int)(j >> 9);          // 512 units per row (2048/4)
      const int c0 = ((int)j & 511) * 4;    // int column; group = c0/64 (4 | 64)
      const int g = c0 >> 6;
      const float s = scales[o * NG + g];
      const float zs = -zeros[o * NG + g] * s;
      const i32x4 q = __builtin_nontemporal_load((const i32x4*)QW + j);
      union { u16 t[8]; int4 v; } u;
#pragma unroll
      for (int k = 0; k < 4; ++k) {
        u.t[2 * k]     = f2bf(fmaf((float)(q[k] & 15), s, zs));
        u.t[2 * k + 1] = f2bf(fmaf((float)((q[k] >> 4) & 15), s, zs));
      }
      ((int4*)Wb)[j] = u.v;                 // bf16 cols [2*c0, 2*c0+8)
    }
  }
}

// ---------------- main GEMM: r7 structure, conflict-fixed swizzle ----------------
// ONLY change vs r7: the LDS XOR-swizzle gains the missing row bits.
//   swz(row) = (row&7) ^ ((row>>3)&3);  phys_granule = logical ^ swz(row)
// r7's swz used only row&7: in the 32x32 read pattern lanes {l,l+8,l+16,l+24}
// share rr32&7 AND the granule constant -> 4 lanes on one 4-bank set ->
// 6.76e7 conflict cycles/dispatch (~4 extra cyc per ds_read_b128). With the
// (row>>3)&3 term those 4 rows map to 4 distinct granules; within any 16-lane
// group each granule is hit <=2x -- the structure that measured ZERO conflicts
// in the 16x16 layout. Legality: staging bases R0 are multiples of 64 and all
// frag-read row bases are multiples of 32, so (base>>3)&3 == 0 and swz depends
// only on the in-call row offset on both sides.
//
// 32x32x16 fragment mapping (unchanged, verified r7):
//   A: m = lane&31, k = (lane>>5)*8 + j;  B symmetric
//   C/D: col = lane&31, row = (reg&3) + 8*(reg>>2) + 4*(lane>>5), reg in [0,16)
//
// Region/stage/wait schedule (= r6/r7; audit carries):
//   ph0: B1.h1(t+1)+VMCNT(4)  ph1: A1.mh0(t+1)  ph2: A1.mh1(t+1)
//   ph3: B0.h0(t+2)+VMCNT(4)  ph4: B0.h1(t+2)+VMCNT(4)
//   ph5: A0.mh0(t+2)          ph6: A0.mh1(t+2)  ph7: B1.h0(t+3)+VMCNT(4)
// Waits AFTER the MFMA cluster; every wait targets loads >=2 phases old.

__global__ __launch_bounds__(512, 2) void gemm_pre512(const u16* __restrict__ A,
                                                      const u16* __restrict__ B,
                                                      const float* __restrict__ bias,
                                                      float* __restrict__ C) {
  __shared__ __align__(16) u16 As[2][BM * BK];   // 2 x 32 KB
  __shared__ __align__(16) u16 Bs[2][BN * BK];   // 2 x 32 KB  (total 128 KB)
  const int tid = threadIdx.x;
  const int lane = tid & 63;
  const int wid = __builtin_amdgcn_readfirstlane(tid >> 6);

  // XCD-local 2D grouping (r6): XCD k owns bm in [4k,4k+4); 4bm x 8bn walks.
  const int lin = blockIdx.x;
  const int xcd = lin & 7;
  const int wgc = lin >> 3;                 // 0..171
  int bmr, bn;
  if (wgc < 160) {
    const int g = wgc >> 5, r = wgc & 31;
    bn = g * 8 + (r & 7);
    bmr = r >> 3;
  } else {
    const int r = wgc - 160;
    bn = 40 + r % 3;
    bmr = r / 3;
  }
  const int bm = xcd * 4 + bmr;

  const u16* Ab = A + (size_t)bm * BM * INF;
  const u16* Bb = B + (size_t)bn * BN * INF;

  // staging addressing: one global_load_lds (all 8 waves) covers 64 rows
  const int rowoff = tid >> 3;                    // 0..63
  const int gran = (tid & 7) ^ (rowoff & 7) ^ ((rowoff >> 3) & 3);  // pre-swizzled src granule
  const u16* Asrc = Ab + (size_t)rowoff * INF + gran * 8;
  const u16* Bsrc = Bb + (size_t)rowoff * INF + gran * 8;
  const int wid8 = wid * 8;

  // frag addressing (32x32)
  const int rr32 = lane & 31;
  const int hi = lane >> 5;
  const int xr = (rr32 & 7) ^ ((rr32 >> 3) & 3);  // swz(row): read-side XOR
  const int wm = wid >> 2;   // 0..1 -> 128-row half of A tile
  const int wn = wid & 3;    // 0..3 -> 64-row quarter of B tile

  f32x16 acc[4][2] = {};     // [m-tile 0..3][n-tile 0..1], 128 VGPRs
  bf16x8 bq[2][2];           // B frags [nt][ks] for current KS2 (live 2 phases)

// single 64-row staging call (1 VMEM instr/wave; wave w covers rows R0+8w..+7)
#define STAGE1(LDS, SRC, TT, R0)                                               \
  async_copy16((SRC) + (size_t)(R0) * INF + (size_t)(TT) * BK,                 \
               (const char*)(LDS) + ((R0) + wid8) * 128);

// 4 ds_read_b128: A frags [mi][ks] for (KS2, MH) -- rows wm*128+MH*64..+64
#define RD_A(DST, S, KS2, MH)                                                  \
  _Pragma("unroll") for (int mi = 0; mi < 2; ++mi)                             \
    _Pragma("unroll") for (int ks = 0; ks < 2; ++ks)                           \
      DST[mi][ks] = *(const bf16x8*)&As[S][                                    \
          (wm * 128 + ((MH) * 2 + mi) * 32 + rr32) * BK +                      \
          ((((KS2) * 4 + ks * 2 + hi) ^ xr) * 8)];

// 4 ds_read_b128: B frags [ni][ks] for KS2 -- rows wn*64..+64
#define RD_B(DST, S, KS2)                                                      \
  _Pragma("unroll") for (int ni = 0; ni < 2; ++ni)                             \
    _Pragma("unroll") for (int ks = 0; ks < 2; ++ks)                           \
      DST[ni][ks] = *(const bf16x8*)&Bs[S][                                    \
          (wn * 64 + ni * 32 + rr32) * BK +                                    \
          ((((KS2) * 4 + ks * 2 + hi) ^ xr) * 8)];

// 8 x mfma_f32_32x32x16_bf16: quadrant (MH) x both nt x both ks
#define MFMA8(AF, BQ, MH)                                                      \
  do {                                                                         \
    __builtin_amdgcn_s_setprio(1);                                             \
    _Pragma("unroll") for (int ks = 0; ks < 2; ++ks)                           \
      _Pragma("unroll") for (int mi = 0; mi < 2; ++mi)                         \
        _Pragma("unroll") for (int ni = 0; ni < 2; ++ni)                       \
          acc[(MH) * 2 + mi][ni] = __builtin_amdgcn_mfma_f32_32x32x16_bf16(    \
              AF[mi][ks], BQ[ni][ks], acc[(MH) * 2 + mi][ni], 0, 0, 0);        \
    __builtin_amdgcn_s_setprio(0);                                             \
  } while (0)

  // prologue (r6 verbatim): steady-state tail of a virtual previous iter.
  STAGE1(&As[0][0], Asrc, 0, 0)   STAGE1(&As[0][0], Asrc, 0, 128)
  STAGE1(&Bs[0][0], Bsrc, 0, 0)   STAGE1(&Bs[0][0], Bsrc, 0, 64)
  STAGE1(&Bs[0][0], Bsrc, 0, 128) STAGE1(&Bs[0][0], Bsrc, 0, 192)
  STAGE1(&As[0][0], Asrc, 0, 64)  STAGE1(&As[0][0], Asrc, 0, 192)
  STAGE1(&Bs[1][0], Bsrc, 1, 0)   STAGE1(&Bs[1][0], Bsrc, 1, 64)
  VMCNT(4);
  BAR();

  for (int t = 0; t < NT; t += 2) {
    // ph0: slot0 (KS2=0,MH0) | stage B1.h1(t+1) | VMCNT(4) post-MFMA
    {
      bf16x8 af[2][2];
      RD_A(af, 0, 0, 0) RD_B(bq, 0, 0)
      STAGE1(&Bs[1][0], Bsrc, t + 1, 128) STAGE1(&Bs[1][0], Bsrc, t + 1, 192)
      BAR(); MFMA8(af, bq, 0);
      VMCNT(4);
      BAR();
    }
    // ph1: slot0 (KS2=0,MH1) | stage A1.mh0(t+1)
    {
      bf16x8 af[2][2];
      RD_A(af, 0, 0, 1)
      STAGE1(&As[1][0], Asrc, t + 1, 0) STAGE1(&As[1][0], Asrc, t + 1, 128)
      BAR(); MFMA8(af, bq, 1); BAR();
    }
    // ph2: slot0 (KS2=1,MH0) | stage A1.mh1(t+1)
    {
      bf16x8 af[2][2];
      RD_A(af, 0, 1, 0) RD_B(bq, 0, 1)
      STAGE1(&As[1][0], Asrc, t + 1, 64) STAGE1(&As[1][0], Asrc, t + 1, 192)
      BAR(); MFMA8(af, bq, 0); BAR();
    }
    // ph3: slot0 (KS2=1,MH1) | stage B0.h0(t+2) | VMCNT(4) post-MFMA
    {
      bf16x8 af[2][2];
      RD_A(af, 0, 1, 1)
      if (t + 2 < NT) { STAGE1(&Bs[0][0], Bsrc, t + 2, 0) STAGE1(&Bs[0][0], Bsrc, t + 2, 64) }
      BAR(); MFMA8(af, bq, 1);
      if (t + 2 < NT) { VMCNT(4); } else { VMCNT(0); }
      BAR();
    }
    // ph4: slot1 (KS2=0,MH0) | stage B0.h1(t+2) | VMCNT(4) post-MFMA
    {
      bf16x8 af[2][2];
      RD_A(af, 1, 0, 0) RD_B(bq, 1, 0)
      if (t + 2 < NT) { STAGE1(&Bs[0][0], Bsrc, t + 2, 128) STAGE1(&Bs[0][0], Bsrc, t + 2, 192) }
      BAR(); MFMA8(af, bq, 0);
      if (t + 2 < NT) { VMCNT(4); } else { VMCNT(0); }
      BAR();
    }
    // ph5: slot1 (KS2=0,MH1) | stage A0.mh0(t+2)
    {
      bf16x8 af[2][2];
      RD_A(af, 1, 0, 1)
      if (t + 2 < NT) { STAGE1(&As[0][0], Asrc, t + 2, 0) STAGE1(&As[0][0], Asrc, t + 2, 128) }
      BAR(); MFMA8(af, bq, 1); BAR();
    }
    // ph6: slot1 (KS2=1,MH0) | stage A0.mh1(t+2)
    {
      bf16x8 af[2][2];
      RD_A(af, 1, 1, 0) RD_B(bq, 1, 1)
      if (t + 2 < NT) { STAGE1(&As[0][0], Asrc, t + 2, 64) STAGE1(&As[0][0], Asrc, t + 2, 192) }
      BAR(); MFMA8(af, bq, 0); BAR();
    }
    // ph7: slot1 (KS2=1,MH1) | stage B1.h0(t+3) | VMCNT(4) post-MFMA
    {
      bf16x8 af[2][2];
      RD_A(af, 1, 1, 1)
      if (t + 2 < NT) { STAGE1(&Bs[1][0], Bsrc, t + 3, 0) STAGE1(&Bs[1][0], Bsrc, t + 3, 64) }
      BAR(); MFMA8(af, bq, 1);
      if (t + 2 < NT) { VMCNT(4); } else { VMCNT(0); }
      BAR();
    }
  }

  // epilogue: NT stores; 32x32 C/D layout col=lane&31,
  // row = (reg&3) + 8*(reg>>2) + 4*hi
  float bv[2];
#pragma unroll
  for (int ni = 0; ni < 2; ++ni)
    bv[ni] = bias[bn * BN + wn * 64 + ni * 32 + rr32];
#pragma unroll
  for (int mt = 0; mt < 4; ++mt)
#pragma unroll
    for (int ni = 0; ni < 2; ++ni) {
      const int gn = bn * BN + wn * 64 + ni * 32 + rr32;
#pragma unroll
      for (int reg = 0; reg < 16; ++reg) {
        const int gm = bm * BM + wm * 128 + mt * 32 +
                       (reg & 3) + 8 * (reg >> 2) + 4 * hi;
        __builtin_nontemporal_store(acc[mt][ni][reg] + bv[ni],
                                    &C[(size_t)gm * OUTF + gn]);
      }
    }
}

// ---------------- fused fallback (no workspace requirement) ----------------

#define FBM 128
#define FBN 128

#define FMFMA_COMPUTE()                                                       \
  do {                                                                        \
    const int frr = lane & 15;                                                \
    const int fq4 = lane >> 4;                                                \
    _Pragma("unroll") for (int ks = 0; ks < 2; ++ks) {                        \
      bf16x8 fa[4], fb[4];                                                    \
      const int kk = (((ks * 4 + fq4) ^ (frr & 7)) * 8);                      \
      _Pragma("unroll") for (int i = 0; i < 4; ++i) {                         \
        fa[i] = *(const bf16x8*)&Asf[(mwave + i * 16 + frr) * BK + kk];       \
        fb[i] = *(const bf16x8*)&Bsf[(nwave + i * 16 + frr) * BK + kk];       \
      }                                                                       \
      _Pragma("unroll") for (int mi = 0; mi < 4; ++mi)                        \
        _Pragma("unroll") for (int ni = 0; ni < 4; ++ni)                      \
          facc[mi][ni] = __builtin_amdgcn_mfma_f32_16x16x32_bf16(             \
              fa[mi], fb[ni], facc[mi][ni], 0, 0, 0);                         \
    }                                                                         \
  } while (0)

__global__ __launch_bounds__(256) void gemm_fused(const float* __restrict__ X,
                                                  const int* __restrict__ QW,
                                                  const float* __restrict__ scales,
                                                  const float* __restrict__ zeros,
                                                  const float* __restrict__ bias,
                                                  float* __restrict__ C) {
  __shared__ __align__(16) u16 Asf[FBM * BK];
  __shared__ __align__(16) u16 Bsf[FBN * BK];
  const int tid = threadIdx.x;
  const int lane = tid & 63;
  const int wid = tid >> 6;
  const int bm = blockIdx.y, bn = blockIdx.x;
  const int row = tid >> 1;
  const int half = tid & 1;
  const float* xr = X + (size_t)(bm * FBM + row) * INF + half * 32;
  const int* qr = QW + (size_t)(bn * FBN + row) * KB4 + half * 16;
  const float* srow = scales + (size_t)(bn * FBN + row) * NG;
  const float* zrow = zeros + (size_t)(bn * FBN + row) * NG;
  const int mwave = (wid >> 1) * 64;
  const int nwave = (wid & 1) * 64;
  f32x4 facc[4][4] = {};

  for (int kb = 0; kb < INF / BK; ++kb) {
    const int k0 = kb * BK;
    union { u16 t[32]; int4 v[4]; } ta, tb;
#pragma unroll
    for (int j = 0; j < 8; ++j) {
      const float4 f = *(const float4*)(xr + k0 + j * 4);
      ta.t[4 * j]     = f2bf(f.x);
      ta.t[4 * j + 1] = f2bf(f.y);
      ta.t[4 * j + 2] = f2bf(f.z);
      ta.t[4 * j + 3] = f2bf(f.w);
    }
    {
      const float s = srow[kb >> 1];
      const float zs = -zrow[kb >> 1] * s;
#pragma unroll
      for (int j = 0; j < 4; ++j) {
        const int4 q = *(const int4*)(qr + kb * 32 + j * 4);
        const int qq[4] = {q.x, q.y, q.z, q.w};
#pragma unroll
        for (int u = 0; u < 4; ++u) {
          tb.t[8 * j + 2 * u]     = f2bf(fmaf((float)(qq[u] & 15), s, zs));
          tb.t[8 * j + 2 * u + 1] = f2bf(fmaf((float)((qq[u] >> 4) & 15), s, zs));
        }
      }
    }
    __syncthreads();
#pragma unroll
    for (int j = 0; j < 4; ++j) {
      *(int4*)&Asf[row * BK + (((half * 4 + j) ^ (row & 7)) * 8)] = ta.v[j];
      *(int4*)&Bsf[row * BK + (((half * 4 + j) ^ (row & 7)) * 8)] = tb.v[j];
    }
    __syncthreads();
    FMFMA_COMPUTE();
  }
  {
    const int ncol = lane & 15;
    const int qrow = (lane >> 4) * 4;
#pragma unroll
    for (int mi = 0; mi < 4; ++mi)
#pragma unroll
      for (int ni = 0; ni < 4; ++ni) {
        const int gn = bn * FBN + nwave + ni * 16 + ncol;
        const float bvv = bias[gn];
#pragma unroll
        for (int r = 0; r < 4; ++r) {
          const int gm = bm * FBM + mwave + mi * 16 + qrow + r;
          C[(size_t)gm * OUTF + gn] = facc[mi][ni][r] + bvv;
        }
      }
  }
}

// ---------------- launch ----------------

extern "C" void kernel_launch(void* const* d_in, const int* in_sizes, int n_in,
                              void* d_out, int out_size, void* d_ws, size_t ws_size,
                              hipStream_t stream) {
  const float* x = (const float*)d_in[0];
  const int* qw = (const int*)d_in[1];
  const float* scales = (const float*)d_in[2];
  const float* zeros = (const float*)d_in[3];
  const float* bias = (const float*)d_in[4];
  float* out = (float*)d_out;

  const size_t needW = (size_t)OUTF * INF * sizeof(u16);  // 90,177,536 B
  const size_t needX = (size_t)TOK * INF * sizeof(u16);   // 67,108,864 B

  if (ws_size >= needW + needX) {
    u16* Wb = (u16*)d_ws;
    u16* Xb = (u16*)((char*)d_ws + needW);
    prep<<<PREPBLK, 256, 0, stream>>>(x, qw, scales, zeros, Xb, Wb);
    gemm_pre512<<<dim3(NWG), 512, 0, stream>>>(Xb, Wb, bias, out);
  } else {
    gemm_fused<<<dim3(OUTF / FBN, TOK / FBM), 256, 0, stream>>>(x, qw, scales, zeros, bias, out);
  }
}